// Round 18
// baseline (135.696 us; speedup 1.0000x reference)
//
#include <hip/hip_runtime.h>

#define N_OP   50000
#define N_MAC  2000
#define IN_OP  64
#define IN_MAC 32
#define OUT    128
#define HEADS  4
#define DK     32
#define ATT_DIM 65
#define E_SEQ  150000
#define E_OM   300000
#define E_MO   300000
#define E_SM   (E_SEQ + E_MO)
#define TOT_E  (E_SEQ + E_MO + E_OM)
#define EPS    1e-6f
#define LN_EPS 1e-5f
#define NXCD   8

#define TILES_OP  (N_OP / 16)            // 3125
#define TILES_MAC (N_MAC / 16)           // 125
#define GBA ((TILES_OP + 3) / 4)         // 782
#define GBB ((TILES_MAC + 3) / 4)        // 32
#define HBK ((TOT_E + 511) / 512)        // 1465

#define AB_OP   ((N_OP + 255) / 256)
#define AB_OM   ((N_MAC + 255) / 256)
#define AB_TOT  (AB_OP + AB_OM)

#define FOM_B   ((E_OM + 511) / 512)     // fill_om blocks (2 edges/thread)
#define FSM_B   ((E_SM + 511) / 512)     // fill_sm blocks (2 edges/thread)
#define GOP_B   ((N_OP + 3) / 4)         // 12500 gather_op blocks

typedef unsigned short ushort_t;
typedef unsigned int   uint_t;
typedef __attribute__((ext_vector_type(8))) short bf16x8;
typedef __attribute__((ext_vector_type(4))) float f32x4;

__device__ __forceinline__ ushort_t f32_to_bf16_rtne(float f) {
    uint_t u = __float_as_uint(f);
    u += 0x7FFFu + ((u >> 16) & 1u);
    return (ushort_t)(u >> 16);
}

__device__ __forceinline__ bf16x8 cvt8(float4 a, float4 b) {
    bf16x8 r;
    r[0] = (short)f32_to_bf16_rtne(a.x); r[1] = (short)f32_to_bf16_rtne(a.y);
    r[2] = (short)f32_to_bf16_rtne(a.z); r[3] = (short)f32_to_bf16_rtne(a.w);
    r[4] = (short)f32_to_bf16_rtne(b.x); r[5] = (short)f32_to_bf16_rtne(b.y);
    r[6] = (short)f32_to_bf16_rtne(b.z); r[7] = (short)f32_to_bf16_rtne(b.w);
    return r;
}

__device__ __forceinline__ uint_t my_xcd() {
    uint_t x;
    asm volatile("s_getreg_b32 %0, hwreg(HW_REG_XCC_ID)" : "=s"(x));
    return x & (NXCD - 1);
}

__device__ __forceinline__ int l2_atomic_inc(int* p) {
    return __hip_atomic_fetch_add(p, 1, __ATOMIC_RELAXED, __HIP_MEMORY_SCOPE_WORKGROUP);
}

// ---------------------------------------------------------------------------
// K0: block 0 folds attention through W (Ub bf16, c f32); blocks >=1 zero
// replica counters + ctr.
// ---------------------------------------------------------------------------
__global__ void k_fold_zero(const float* __restrict__ W_op, const float* __restrict__ b_op,
                            const float* __restrict__ W_mac, const float* __restrict__ b_mac,
                            const float* __restrict__ att_seq, const float* __restrict__ att_om,
                            const float* __restrict__ att_mo,
                            float* __restrict__ c_op, float* __restrict__ c_mac,
                            ushort_t* __restrict__ Ub_op, ushort_t* __restrict__ Ub_mac,
                            int* __restrict__ zero_base) {
    const int t = threadIdx.x;
    if (blockIdx.x == 0) {
        for (int idx = t; idx < 16 * IN_OP; idx += 256) {
            const int j = idx >> 6, k = idx & 63;
            const int hd = j & 3, pr = j >> 2;
            const float* att = (pr <= 1) ? att_seq : (pr == 2 ? att_om : att_mo);
            const int off = (pr == 1 || pr == 3) ? 32 : 0;
            float s = 0.f;
            for (int l = 0; l < 32; ++l)
                s += att[hd * ATT_DIM + off + l] * W_op[(hd * 32 + l) * IN_OP + k];
            Ub_op[idx] = f32_to_bf16_rtne(s);
        }
        if (t < 16) {
            const int hd = t & 3, pr = t >> 2;
            const float* att = (pr <= 1) ? att_seq : (pr == 2 ? att_om : att_mo);
            const int off = (pr == 1 || pr == 3) ? 32 : 0;
            float s = 0.f;
            for (int l = 0; l < 32; ++l) s += att[hd * ATT_DIM + off + l] * b_op[hd * 32 + l];
            c_op[t] = s;
        }
        for (int idx = t; idx < 8 * IN_MAC; idx += 256) {
            const int j = idx >> 5, k = idx & 31;
            const int hd = j & 3, pr = j >> 2;
            const float* att = (pr == 0) ? att_om : att_mo;
            const int off = (pr == 0) ? 32 : 0;
            float s = 0.f;
            for (int l = 0; l < 32; ++l)
                s += att[hd * ATT_DIM + off + l] * W_mac[(hd * 32 + l) * IN_MAC + k];
            Ub_mac[idx] = f32_to_bf16_rtne(s);
        }
        for (int idx = 8 * IN_MAC + t; idx < 16 * IN_MAC; idx += 256) Ub_mac[idx] = 0;
        if (t < 8) {
            const int hd = t & 3, pr = t >> 2;
            const float* att = (pr == 0) ? att_om : att_mo;
            const int off = (pr == 0) ? 32 : 0;
            float s = 0.f;
            for (int l = 0; l < 32; ++l) s += att[hd * ATT_DIM + off + l] * b_mac[hd * 32 + l];
            c_mac[t] = s;
        }
    } else {
        const int n = NXCD * (N_OP + N_MAC) + 4;
        for (int i = (blockIdx.x - 1) * 256 + t; i < n; i += 63 * 256)
            zero_base[i] = 0;
    }
}

// ---------------------------------------------------------------------------
// K1: [gemm op | gemm mac | histo+rank]. GEMM converts f32->bf16 fragments
// in-register; writes bf16 z only. Histo: combined seq+mo counter per op row,
// om separate; per-XCD replicas with L2-local returning atomics; rank packs
// (xcd<<24)|local_rank.
// ---------------------------------------------------------------------------
__global__ void k_gemm_histo(
    const float* __restrict__ h_op, const float* __restrict__ W_op, const float* __restrict__ b_op,
    const float* __restrict__ h_mac, const float* __restrict__ W_mac, const float* __restrict__ b_mac,
    const ushort_t* __restrict__ Ub_op, const float* __restrict__ c_op,
    const ushort_t* __restrict__ Ub_mac, const float* __restrict__ c_mac,
    ushort_t* __restrict__ zb_op, ushort_t* __restrict__ zb_mac,
    float* __restrict__ p_op, float* __restrict__ p_mac,
    const int* __restrict__ seq_dst, const int* __restrict__ mo_dst, const int* __restrict__ om_dst,
    int* __restrict__ crep_op, int* __restrict__ crep_om,
    int* __restrict__ rank_all) {
    const int bid = blockIdx.x;
    const int t = threadIdx.x;
    const int w = t >> 6, l = t & 63;
    const int li = l & 15, lg = l >> 4;

    if (bid < GBA) {
        const int tile = bid * 4 + w;
        if (tile >= TILES_OP) return;
        const int row0 = tile * 16;
        const float* hr = h_op + (size_t)(row0 + li) * IN_OP + lg * 8;
        const bf16x8 a0 = cvt8(*reinterpret_cast<const float4*>(hr),
                               *reinterpret_cast<const float4*>(hr + 4));
        const bf16x8 a1 = cvt8(*reinterpret_cast<const float4*>(hr + 32),
                               *reinterpret_cast<const float4*>(hr + 36));
        const int orow = row0 + lg * 4;
#pragma unroll
        for (int ct = 0; ct < 8; ++ct) {
            const int col = ct * 16 + li;
            const float* wr = W_op + (size_t)col * IN_OP + lg * 8;
            const bf16x8 b0 = cvt8(*reinterpret_cast<const float4*>(wr),
                                   *reinterpret_cast<const float4*>(wr + 4));
            const bf16x8 b1 = cvt8(*reinterpret_cast<const float4*>(wr + 32),
                                   *reinterpret_cast<const float4*>(wr + 36));
            f32x4 acc = {0.f, 0.f, 0.f, 0.f};
            acc = __builtin_amdgcn_mfma_f32_16x16x32_bf16(a0, b0, acc, 0, 0, 0);
            acc = __builtin_amdgcn_mfma_f32_16x16x32_bf16(a1, b1, acc, 0, 0, 0);
            const float bias = b_op[col];
#pragma unroll
            for (int r = 0; r < 4; ++r)
                zb_op[(size_t)(orow + r) * OUT + col] = f32_to_bf16_rtne(acc[r] + bias);
        }
        {
            const bf16x8 u0 = *reinterpret_cast<const bf16x8*>(Ub_op + (size_t)li * IN_OP + lg * 8);
            const bf16x8 u1 = *reinterpret_cast<const bf16x8*>(Ub_op + (size_t)li * IN_OP + lg * 8 + 32);
            f32x4 acc = {0.f, 0.f, 0.f, 0.f};
            acc = __builtin_amdgcn_mfma_f32_16x16x32_bf16(a0, u0, acc, 0, 0, 0);
            acc = __builtin_amdgcn_mfma_f32_16x16x32_bf16(a1, u1, acc, 0, 0, 0);
            const float cj = c_op[li];
#pragma unroll
            for (int r = 0; r < 4; ++r)
                p_op[(size_t)(orow + r) * 16 + li] = acc[r] + cj;
        }
    } else if (bid < GBA + GBB) {
        const int tile = (bid - GBA) * 4 + w;
        if (tile >= TILES_MAC) return;
        const int row0 = tile * 16;
        const float* hr = h_mac + (size_t)(row0 + li) * IN_MAC + lg * 8;
        const bf16x8 a0 = cvt8(*reinterpret_cast<const float4*>(hr),
                               *reinterpret_cast<const float4*>(hr + 4));
        const int orow = row0 + lg * 4;
#pragma unroll
        for (int ct = 0; ct < 8; ++ct) {
            const int col = ct * 16 + li;
            const float* wr = W_mac + (size_t)col * IN_MAC + lg * 8;
            const bf16x8 b0 = cvt8(*reinterpret_cast<const float4*>(wr),
                                   *reinterpret_cast<const float4*>(wr + 4));
            f32x4 acc = {0.f, 0.f, 0.f, 0.f};
            acc = __builtin_amdgcn_mfma_f32_16x16x32_bf16(a0, b0, acc, 0, 0, 0);
            const float bias = b_mac[col];
#pragma unroll
            for (int r = 0; r < 4; ++r)
                zb_mac[(size_t)(orow + r) * OUT + col] = f32_to_bf16_rtne(acc[r] + bias);
        }
        {
            const bf16x8 u0 = *reinterpret_cast<const bf16x8*>(Ub_mac + (size_t)li * IN_MAC + lg * 8);
            f32x4 acc = {0.f, 0.f, 0.f, 0.f};
            acc = __builtin_amdgcn_mfma_f32_16x16x32_bf16(a0, u0, acc, 0, 0, 0);
            if (li < 8) {
                const float cj = c_mac[li];
#pragma unroll
                for (int r = 0; r < 4; ++r)
                    p_mac[(size_t)(orow + r) * 8 + li] = acc[r] + cj;
            }
        }
    } else {
        const uint_t x = my_xcd();
        int* const cop = crep_op + x * N_OP;
        int* const com = crep_om + x * N_MAC;
        const int base = (bid - GBA - GBB) * 512 + t;
#pragma unroll
        for (int k = 0; k < 2; ++k) {
            const int ge = base + k * 256;
            int r;
            if (ge < E_SEQ) {
                r = l2_atomic_inc(&cop[seq_dst[ge]]);
                rank_all[ge] = (int)((x << 24) | (uint_t)r);
            } else if (ge < E_SM) {
                r = l2_atomic_inc(&cop[mo_dst[ge - E_SEQ]]);
                rank_all[ge] = (int)((x << 24) | (uint_t)r);
            } else if (ge < TOT_E) {
                r = l2_atomic_inc(&com[om_dst[ge - E_SM]]);
                rank_all[ge] = (int)((x << 24) | (uint_t)r);
            }
        }
    }
}

// ---------------------------------------------------------------------------
// K2: alloc. Per dst: total = sum of 8 replicas; wave-scan totals -> sta/end;
// per-replica bases brep[x][d] = sta[d] + prefix_x.
// ---------------------------------------------------------------------------
__global__ void k_alloc(const int* __restrict__ crep_op, int* __restrict__ sta_op, int* __restrict__ end_op, int* __restrict__ brep_op,
                        const int* __restrict__ crep_om, int* __restrict__ sta_om, int* __restrict__ end_om, int* __restrict__ brep_om,
                        int* __restrict__ ctr) {
    const int b = blockIdx.x, t = threadIdx.x;
    const int* crep; int* sta; int* end; int* brep; int n, g, lb;
    if (b < AB_OP) { crep = crep_op; sta = sta_op; end = end_op; brep = brep_op; n = N_OP;  g = 0; lb = b; }
    else           { crep = crep_om; sta = sta_om; end = end_om; brep = brep_om; n = N_MAC; g = 1; lb = b - AB_OP; }
    const int d = lb * 256 + t;
    const int lane = t & 63;
    int c[NXCD];
    int tot = 0;
#pragma unroll
    for (int x = 0; x < NXCD; ++x) {
        c[x] = (d < n) ? crep[x * n + d] : 0;
        tot += c[x];
    }
    int xs = tot;
#pragma unroll
    for (int m = 1; m < 64; m <<= 1) {
        int y = __shfl_up(xs, m);
        if (lane >= m) xs += y;
    }
    int base = 0;
    if (lane == 63) base = atomicAdd(&ctr[g], xs);
    base = __shfl(base, 63);
    if (d < n) {
        const int s = base + xs - tot;
        sta[d] = s;
        end[d] = s + tot;
        int acc = s;
#pragma unroll
        for (int x = 0; x < NXCD; ++x) {
            brep[x * n + d] = acc;
            acc += c[x];
        }
    }
}

// ---------------------------------------------------------------------------
// Fill body: record {arena_row|flag<<31, al01, al23, 0};
// pos = brep[xcd][d] + local_rank.
// ---------------------------------------------------------------------------
__device__ __forceinline__ void fill_one(uint_t rowtag, int d, float f,
                                         const float* __restrict__ ps, int pso,
                                         const float* __restrict__ pd, int pdo,
                                         const float* __restrict__ att,
                                         const int* __restrict__ brep, int n, int ri,
                                         uint4* __restrict__ rec) {
    const float4 as = *reinterpret_cast<const float4*>(ps + pso);
    const float4 ad = *reinterpret_cast<const float4*>(pd + pdo);
    const float4 aw = make_float4(att[64], att[ATT_DIM + 64], att[2 * ATT_DIM + 64], att[3 * ATT_DIM + 64]);
    const float sc[4] = {as.x + ad.x + f * aw.x, as.y + ad.y + f * aw.y,
                         as.z + ad.z + f * aw.z, as.w + ad.w + f * aw.w};
    uint_t b16[4];
#pragma unroll
    for (int hh = 0; hh < 4; ++hh) {
        float v = sc[hh];
        v = (v >= 0.f) ? v : 0.2f * v;
        v = fminf(fmaxf(v, -20.f), 20.f);
        b16[hh] = f32_to_bf16_rtne(expf(v));
    }
    const int xcd = ((uint_t)ri) >> 24;
    const int rank = ri & 0xFFFFFF;
    const int pos = brep[xcd * n + d] + rank;
    uint4 r;
    r.x = rowtag;
    r.y = b16[0] | (b16[1] << 16);
    r.z = b16[2] | (b16[3] << 16);
    r.w = 0;
    rec[pos] = r;
}

__device__ __forceinline__ void fill_sm_edge(
    int ge,
    const int* __restrict__ seq_src, const int* __restrict__ seq_dst, const float* __restrict__ feat_seq,
    const int* __restrict__ mo_src,  const int* __restrict__ mo_dst,  const float* __restrict__ feat_mo,
    const float* __restrict__ p_op, const float* __restrict__ p_mac,
    const float* __restrict__ att_seq, const float* __restrict__ att_mo,
    const int* __restrict__ brep_op, const int* __restrict__ rank_all,
    uint4* __restrict__ rec_op) {
    if (ge < E_SEQ) {
        const int s = seq_src[ge], d = seq_dst[ge];
        fill_one((uint_t)s, d, feat_seq[ge], p_op, s * 16 + 0, p_op, d * 16 + 4,
                 att_seq, brep_op, N_OP, rank_all[ge], rec_op);
    } else if (ge < E_SM) {
        const int e = ge - E_SEQ;
        const int s = mo_src[e], d = mo_dst[e];
        fill_one((uint_t)(N_OP + s) | 0x80000000u, d, feat_mo[e], p_mac, s * 8 + 4,
                 p_op, d * 16 + 12, att_mo, brep_op, N_OP, rank_all[ge], rec_op);
    }
}

// K3: fill om edges only (2 per thread).
__global__ void k_fill_om(
    const int* __restrict__ om_src, const int* __restrict__ om_dst, const float* __restrict__ feat_om,
    const float* __restrict__ p_op, const float* __restrict__ p_mac,
    const float* __restrict__ att_om,
    const int* __restrict__ brep_om, const int* __restrict__ rank_all,
    uint4* __restrict__ rec_om) {
    const int base = blockIdx.x * 512 + threadIdx.x;
#pragma unroll
    for (int k = 0; k < 2; ++k) {
        const int e = base + k * 256;
        if (e < E_OM) {
            const int s = om_src[e], d = om_dst[e];
            fill_one((uint_t)s, d, feat_om[e], p_op, s * 16 + 8, p_mac, d * 8 + 0,
                     att_om, brep_om, N_MAC, rank_all[E_SM + e], rec_om);
        }
    }
}

// ---------------------------------------------------------------------------
// Gather helpers.
// ---------------------------------------------------------------------------
__device__ __forceinline__ float2 ln_elu2(float x0, float x1, int lane,
                                          const float* __restrict__ g,
                                          const float* __restrict__ bb, int col2) {
    float s = x0 + x1;
#pragma unroll
    for (int m = 32; m >= 1; m >>= 1) s += __shfl_xor(s, m);
    const float mu = s * (1.0f / OUT);
    const float dx0 = x0 - mu, dx1 = x1 - mu;
    float q = dx0 * dx0 + dx1 * dx1;
#pragma unroll
    for (int m = 32; m >= 1; m >>= 1) q += __shfl_xor(q, m);
    const float r = rsqrtf(q * (1.0f / OUT) + LN_EPS);
    const float2 g2 = *reinterpret_cast<const float2*>(g + col2);
    const float2 b2 = *reinterpret_cast<const float2*>(bb + col2);
    float y0 = dx0 * r * g2.x + b2.x;
    float y1 = dx1 * r * g2.y + b2.y;
    y0 = (y0 > 0.f) ? y0 : expm1f(y0);
    y1 = (y1 > 0.f) ? y1 : expm1f(y1);
    return make_float2(y0, y1);
}

__device__ __forceinline__ float2 unpack_bf2(uint_t zz) {
    return make_float2(__uint_as_float(zz << 16), __uint_as_float(zz & 0xffff0000u));
}

// Scalarized record-segment accumulate (R17): scalar loop index ->
// s_load_dwordx4 record fetch (SMEM queue), SALU decode, ~11 VALU/record.
__device__ __forceinline__ void seg_scalar(const uint4* __restrict__ rec,
                                           const ushort_t* __restrict__ arena,
                                           int s0, int e0, int wSel, int hiSel, int col2,
                                           float& ns0, float& ns1, float& nm0, float& nm1,
                                           float& ds, float& dm) {
#pragma unroll 8
    for (int i = s0; i < e0; ++i) {
        const uint4 r = rec[i];
        const int row = (int)(r.x & 0x7fffffffu);
        const uint_t isMo = r.x >> 31;
        const uint_t pick = wSel ? r.z : r.y;
        const float a = __uint_as_float(hiSel ? (pick & 0xffff0000u) : (pick << 16));
        const float a_s = isMo ? 0.f : a;
        const float a_m = isMo ? a : 0.f;
        const uint_t zz = *reinterpret_cast<const uint_t*>(arena + (size_t)row * OUT + col2);
        const float z0 = __uint_as_float(zz << 16);
        const float z1 = __uint_as_float(zz & 0xffff0000u);
        ns0 = fmaf(a_s, z0, ns0);
        ns1 = fmaf(a_s, z1, ns1);
        nm0 = fmaf(a_m, z0, nm0);
        nm1 = fmaf(a_m, z1, nm1);
        ds += a_s;
        dm += a_m;
    }
}

// ---------------------------------------------------------------------------
// K4: [gather_mac | fill_sm]. mac rows need only rec_om (filled in K3);
// fill_sm produces rec_op for K5 under the mac gather.
// ---------------------------------------------------------------------------
__global__ void k_gmac_fillsm(
    const uint4* __restrict__ rec_om, const int* __restrict__ sta_om, const int* __restrict__ end_om,
    const ushort_t* __restrict__ zb_op, const ushort_t* __restrict__ zb_mac,
    const float* __restrict__ g_mac, const float* __restrict__ b_mac,
    float* __restrict__ out_mac,
    const int* __restrict__ seq_src, const int* __restrict__ seq_dst, const float* __restrict__ feat_seq,
    const int* __restrict__ mo_src,  const int* __restrict__ mo_dst,  const float* __restrict__ feat_mo,
    const float* __restrict__ p_op, const float* __restrict__ p_mac,
    const float* __restrict__ att_seq, const float* __restrict__ att_mo,
    const int* __restrict__ brep_op, const int* __restrict__ rank_all,
    uint4* __restrict__ rec_op) {
    const int bid = blockIdx.x;
    const int t = threadIdx.x;
    if (bid < N_MAC) {
        const int w = __builtin_amdgcn_readfirstlane(t >> 6);
        const int lane = t & 63;
        const int hd = lane >> 4;
        const int col2 = lane * 2;
        const int wSel = hd >> 1, hiSel = hd & 1;
        __shared__ float nsh[4][OUT];
        __shared__ float dsh[4][2 * HEADS];
        const int d = __builtin_amdgcn_readfirstlane(bid);
        const int s0 = sta_om[d], e0 = end_om[d];
        const int len = e0 - s0;
        const int quarter = (len + 3) >> 2;
        const int i0 = s0 + w * quarter;
        int i1 = i0 + quarter;
        if (i1 > e0) i1 = e0;
        float ns0 = 0.f, ns1 = 0.f, nm0 = 0.f, nm1 = 0.f, ds = 0.f, dm = 0.f;
        if (i0 < e0)
            seg_scalar(rec_om, zb_op, i0, i1, wSel, hiSel, col2, ns0, ns1, nm0, nm1, ds, dm);
        nsh[w][col2] = ns0;
        nsh[w][col2 + 1] = ns1;
        if ((lane & 15) == 0) dsh[w][hd] = ds;
        __syncthreads();
        if (w == 0) {
            const float n0 = nsh[0][col2] + nsh[1][col2] + nsh[2][col2] + nsh[3][col2];
            const float n1 = nsh[0][col2 + 1] + nsh[1][col2 + 1] + nsh[2][col2 + 1] + nsh[3][col2 + 1];
            const float dt = dsh[0][hd] + dsh[1][hd] + dsh[2][hd] + dsh[3][hd];
            const float inv = 1.0f / (dt + EPS);
            const float2 zr = unpack_bf2(*reinterpret_cast<const uint_t*>(zb_mac + (size_t)d * OUT + col2));
            const float2 o2 = ln_elu2(n0 * inv + zr.x, n1 * inv + zr.y, lane, g_mac, b_mac, col2);
            *reinterpret_cast<float2*>(out_mac + (size_t)d * OUT + col2) = o2;
        }
    } else {
        const int base = (bid - N_MAC) * 512 + t;
#pragma unroll
        for (int k = 0; k < 2; ++k) {
            fill_sm_edge(base + k * 256, seq_src, seq_dst, feat_seq, mo_src, mo_dst, feat_mo,
                         p_op, p_mac, att_seq, att_mo, brep_op, rank_all, rec_op);
        }
    }
}

// ---------------------------------------------------------------------------
// K5: gather_op — 1 row/wave, scalar record loop over merged seq+mo stream.
// ---------------------------------------------------------------------------
__global__ void k_gather_op(
    const uint4* __restrict__ rec_op, const int* __restrict__ sta_op, const int* __restrict__ end_op,
    const ushort_t* __restrict__ zb_op,
    const float* __restrict__ g_op, const float* __restrict__ b_op,
    float* __restrict__ out_op) {
    const int t = threadIdx.x;
    const int w = __builtin_amdgcn_readfirstlane(t >> 6);
    const int lane = t & 63;
    const int hd = lane >> 4;
    const int col2 = lane * 2;
    const int wSel = hd >> 1, hiSel = hd & 1;
    const int d = __builtin_amdgcn_readfirstlane(blockIdx.x * 4 + w);
    if (d >= N_OP) return;
    const int s0 = sta_op[d], e0 = end_op[d];
    float ns0 = 0.f, ns1 = 0.f, nm0 = 0.f, nm1 = 0.f, ds = 0.f, dm = 0.f;
    seg_scalar(rec_op, zb_op, s0, e0, wSel, hiSel, col2, ns0, ns1, nm0, nm1, ds, dm);
    const float invS = 1.0f / (ds + EPS);
    const float invM = 1.0f / (dm + EPS);
    const float acc0 = ns0 * invS + nm0 * invM;
    const float acc1 = ns1 * invS + nm1 * invM;
    const float2 zr = unpack_bf2(*reinterpret_cast<const uint_t*>(zb_op + (size_t)d * OUT + col2));
    const float2 o2 = ln_elu2(acc0 + zr.x, acc1 + zr.y, lane, g_op, b_op, col2);
    *reinterpret_cast<float2*>(out_op + (size_t)d * OUT + col2) = o2;
}

extern "C" void kernel_launch(void* const* d_in, const int* in_sizes, int n_in,
                              void* d_out, int out_size, void* d_ws, size_t ws_size,
                              hipStream_t stream) {
    const float* h_op      = (const float*)d_in[0];
    const float* h_mac     = (const float*)d_in[1];
    const int*   seq_src   = (const int*)d_in[2];
    const int*   seq_dst   = (const int*)d_in[3];
    const int*   om_src    = (const int*)d_in[4];
    const int*   om_dst    = (const int*)d_in[5];
    const int*   mo_src    = (const int*)d_in[6];
    const int*   mo_dst    = (const int*)d_in[7];
    const float* feat_seq  = (const float*)d_in[8];
    const float* feat_om   = (const float*)d_in[9];
    const float* feat_mo   = (const float*)d_in[10];
    const float* W_op_w    = (const float*)d_in[11];
    const float* W_op_b    = (const float*)d_in[12];
    const float* W_mac_w   = (const float*)d_in[13];
    const float* W_mac_b   = (const float*)d_in[14];
    const float* att_seq   = (const float*)d_in[15];
    const float* att_om    = (const float*)d_in[16];
    const float* att_mo    = (const float*)d_in[17];
    const float* ln_op_g   = (const float*)d_in[18];
    const float* ln_op_b   = (const float*)d_in[19];
    const float* ln_mac_g  = (const float*)d_in[20];
    const float* ln_mac_b  = (const float*)d_in[21];

    float* p = (float*)d_ws;
    float* p_op   = p; p += (size_t)N_OP * 16;
    float* p_mac  = p; p += (size_t)N_MAC * 8;
    float* c_op   = p; p += 16;
    float* c_mac  = p; p += 16;
    uint4* rec_op = (uint4*)p; p += (size_t)E_SM * 4;
    uint4* rec_om = (uint4*)p; p += (size_t)E_OM * 4;
    ushort_t* zb_op  = (ushort_t*)p; p += (size_t)N_OP * OUT / 2;
    ushort_t* zb_mac = (ushort_t*)p; p += (size_t)N_MAC * OUT / 2;
    ushort_t* Ub_op  = (ushort_t*)p; p += 16 * IN_OP / 2;
    ushort_t* Ub_mac = (ushort_t*)p; p += 16 * IN_MAC / 2;
    int* q = (int*)p;
    int* crep_op = q; q += NXCD * N_OP;
    int* crep_om = q; q += NXCD * N_MAC;
    int* ctr     = q; q += 4;
    int* sta_op = q; q += N_OP;
    int* sta_om = q; q += N_MAC;
    int* end_op = q; q += N_OP;
    int* end_om = q; q += N_MAC;
    int* brep_op = q; q += NXCD * N_OP;
    int* brep_om = q; q += NXCD * N_MAC;
    int* rank_all = q; q += TOT_E;

    float* out_op  = (float*)d_out;
    float* out_mac = (float*)d_out + (size_t)N_OP * OUT;

    k_fold_zero<<<64, 256, 0, stream>>>(W_op_w, W_op_b, W_mac_w, W_mac_b,
                                        att_seq, att_om, att_mo,
                                        c_op, c_mac, Ub_op, Ub_mac, crep_op);

    k_gemm_histo<<<GBA + GBB + HBK, 256, 0, stream>>>(
        h_op, W_op_w, W_op_b, h_mac, W_mac_w, W_mac_b,
        Ub_op, c_op, Ub_mac, c_mac,
        zb_op, zb_mac, p_op, p_mac,
        seq_dst, mo_dst, om_dst, crep_op, crep_om, rank_all);

    k_alloc<<<AB_TOT, 256, 0, stream>>>(
        crep_op, sta_op, end_op, brep_op,
        crep_om, sta_om, end_om, brep_om, ctr);

    k_fill_om<<<FOM_B, 256, 0, stream>>>(
        om_src, om_dst, feat_om, p_op, p_mac, att_om,
        brep_om, rank_all, rec_om);

    k_gmac_fillsm<<<N_MAC + FSM_B, 256, 0, stream>>>(
        rec_om, sta_om, end_om, zb_op, zb_mac, ln_mac_g, ln_mac_b, out_mac,
        seq_src, seq_dst, feat_seq, mo_src, mo_dst, feat_mo,
        p_op, p_mac, att_seq, att_mo, brep_op, rank_all, rec_op);

    k_gather_op<<<GOP_B, 256, 0, stream>>>(
        rec_op, sta_op, end_op, zb_op, ln_op_g, ln_op_b, out_op);
}

// Round 19
// 124.114 us; speedup vs baseline: 1.0933x; 1.0933x over previous
//
#include <hip/hip_runtime.h>

#define N_OP   50000
#define N_MAC  2000
#define IN_OP  64
#define IN_MAC 32
#define OUT    128
#define HEADS  4
#define DK     32
#define ATT_DIM 65
#define E_SEQ  150000
#define E_OM   300000
#define E_MO   300000
#define E_SM   (E_SEQ + E_MO)
#define TOT_E  (E_SEQ + E_MO + E_OM)
#define EPS    1e-6f
#define LN_EPS 1e-5f
#define NXCD   8

#define TILES_OP  (N_OP / 16)            // 3125
#define TILES_MAC (N_MAC / 16)           // 125
#define GBA ((TILES_OP + 3) / 4)         // 782
#define GBB ((TILES_MAC + 3) / 4)        // 32
#define HBK ((TOT_E + 511) / 512)        // 1465

#define AB_OP   ((N_OP + 255) / 256)
#define AB_OM   ((N_MAC + 255) / 256)
#define AB_TOT  (AB_OP + AB_OM)

#define FALL_B  ((TOT_E + 255) / 256)    // fill blocks (all graphs)
#define GOP_B   ((N_OP + 3) / 4)         // 12500 gather_op blocks

typedef unsigned short ushort_t;
typedef unsigned int   uint_t;
typedef __attribute__((ext_vector_type(8))) short bf16x8;
typedef __attribute__((ext_vector_type(4))) float f32x4;

__device__ __forceinline__ ushort_t f32_to_bf16_rtne(float f) {
    uint_t u = __float_as_uint(f);
    u += 0x7FFFu + ((u >> 16) & 1u);
    return (ushort_t)(u >> 16);
}

__device__ __forceinline__ bf16x8 cvt8(float4 a, float4 b) {
    bf16x8 r;
    r[0] = (short)f32_to_bf16_rtne(a.x); r[1] = (short)f32_to_bf16_rtne(a.y);
    r[2] = (short)f32_to_bf16_rtne(a.z); r[3] = (short)f32_to_bf16_rtne(a.w);
    r[4] = (short)f32_to_bf16_rtne(b.x); r[5] = (short)f32_to_bf16_rtne(b.y);
    r[6] = (short)f32_to_bf16_rtne(b.z); r[7] = (short)f32_to_bf16_rtne(b.w);
    return r;
}

__device__ __forceinline__ uint_t my_xcd() {
    uint_t x;
    asm volatile("s_getreg_b32 %0, hwreg(HW_REG_XCC_ID)" : "=s"(x));
    return x & (NXCD - 1);
}

// L2-local (workgroup-scope) returning atomic — dodges the device-coherence
// atomic wall. SAFE: replica x is only touched by blocks physically on XCD x.
__device__ __forceinline__ int l2_atomic_inc(int* p) {
    return __hip_atomic_fetch_add(p, 1, __ATOMIC_RELAXED, __HIP_MEMORY_SCOPE_WORKGROUP);
}

// ---------------------------------------------------------------------------
// K0: block 0 folds attention through W (Ub bf16, c f32); blocks >=1 zero
// replica counters + ctr.
// ---------------------------------------------------------------------------
__global__ void k_fold_zero(const float* __restrict__ W_op, const float* __restrict__ b_op,
                            const float* __restrict__ W_mac, const float* __restrict__ b_mac,
                            const float* __restrict__ att_seq, const float* __restrict__ att_om,
                            const float* __restrict__ att_mo,
                            float* __restrict__ c_op, float* __restrict__ c_mac,
                            ushort_t* __restrict__ Ub_op, ushort_t* __restrict__ Ub_mac,
                            int* __restrict__ zero_base) {
    const int t = threadIdx.x;
    if (blockIdx.x == 0) {
        for (int idx = t; idx < 16 * IN_OP; idx += 256) {
            const int j = idx >> 6, k = idx & 63;
            const int hd = j & 3, pr = j >> 2;
            const float* att = (pr <= 1) ? att_seq : (pr == 2 ? att_om : att_mo);
            const int off = (pr == 1 || pr == 3) ? 32 : 0;
            float s = 0.f;
            for (int l = 0; l < 32; ++l)
                s += att[hd * ATT_DIM + off + l] * W_op[(hd * 32 + l) * IN_OP + k];
            Ub_op[idx] = f32_to_bf16_rtne(s);
        }
        if (t < 16) {
            const int hd = t & 3, pr = t >> 2;
            const float* att = (pr <= 1) ? att_seq : (pr == 2 ? att_om : att_mo);
            const int off = (pr == 1 || pr == 3) ? 32 : 0;
            float s = 0.f;
            for (int l = 0; l < 32; ++l) s += att[hd * ATT_DIM + off + l] * b_op[hd * 32 + l];
            c_op[t] = s;
        }
        for (int idx = t; idx < 8 * IN_MAC; idx += 256) {
            const int j = idx >> 5, k = idx & 31;
            const int hd = j & 3, pr = j >> 2;
            const float* att = (pr == 0) ? att_om : att_mo;
            const int off = (pr == 0) ? 32 : 0;
            float s = 0.f;
            for (int l = 0; l < 32; ++l)
                s += att[hd * ATT_DIM + off + l] * W_mac[(hd * 32 + l) * IN_MAC + k];
            Ub_mac[idx] = f32_to_bf16_rtne(s);
        }
        for (int idx = 8 * IN_MAC + t; idx < 16 * IN_MAC; idx += 256) Ub_mac[idx] = 0;
        if (t < 8) {
            const int hd = t & 3, pr = t >> 2;
            const float* att = (pr == 0) ? att_om : att_mo;
            const int off = (pr == 0) ? 32 : 0;
            float s = 0.f;
            for (int l = 0; l < 32; ++l) s += att[hd * ATT_DIM + off + l] * b_mac[hd * 32 + l];
            c_mac[t] = s;
        }
    } else {
        const int n = NXCD * (N_OP + N_MAC) + 4;
        for (int i = (blockIdx.x - 1) * 256 + t; i < n; i += 63 * 256)
            zero_base[i] = 0;
    }
}

// ---------------------------------------------------------------------------
// K1: [gemm op | gemm mac | histo+rank]. GEMM converts f32->bf16 fragments
// in-register; writes bf16 z only. Histo: combined seq+mo counter per op row,
// om separate; per-XCD replicas with L2-local returning atomics; rank packs
// (xcd<<24)|local_rank.
// ---------------------------------------------------------------------------
__global__ void k_gemm_histo(
    const float* __restrict__ h_op, const float* __restrict__ W_op, const float* __restrict__ b_op,
    const float* __restrict__ h_mac, const float* __restrict__ W_mac, const float* __restrict__ b_mac,
    const ushort_t* __restrict__ Ub_op, const float* __restrict__ c_op,
    const ushort_t* __restrict__ Ub_mac, const float* __restrict__ c_mac,
    ushort_t* __restrict__ zb_op, ushort_t* __restrict__ zb_mac,
    float* __restrict__ p_op, float* __restrict__ p_mac,
    const int* __restrict__ seq_dst, const int* __restrict__ mo_dst, const int* __restrict__ om_dst,
    int* __restrict__ crep_op, int* __restrict__ crep_om,
    int* __restrict__ rank_all) {
    const int bid = blockIdx.x;
    const int t = threadIdx.x;
    const int w = t >> 6, l = t & 63;
    const int li = l & 15, lg = l >> 4;

    if (bid < GBA) {
        const int tile = bid * 4 + w;
        if (tile >= TILES_OP) return;
        const int row0 = tile * 16;
        const float* hr = h_op + (size_t)(row0 + li) * IN_OP + lg * 8;
        const bf16x8 a0 = cvt8(*reinterpret_cast<const float4*>(hr),
                               *reinterpret_cast<const float4*>(hr + 4));
        const bf16x8 a1 = cvt8(*reinterpret_cast<const float4*>(hr + 32),
                               *reinterpret_cast<const float4*>(hr + 36));
        const int orow = row0 + lg * 4;
#pragma unroll
        for (int ct = 0; ct < 8; ++ct) {
            const int col = ct * 16 + li;
            const float* wr = W_op + (size_t)col * IN_OP + lg * 8;
            const bf16x8 b0 = cvt8(*reinterpret_cast<const float4*>(wr),
                                   *reinterpret_cast<const float4*>(wr + 4));
            const bf16x8 b1 = cvt8(*reinterpret_cast<const float4*>(wr + 32),
                                   *reinterpret_cast<const float4*>(wr + 36));
            f32x4 acc = {0.f, 0.f, 0.f, 0.f};
            acc = __builtin_amdgcn_mfma_f32_16x16x32_bf16(a0, b0, acc, 0, 0, 0);
            acc = __builtin_amdgcn_mfma_f32_16x16x32_bf16(a1, b1, acc, 0, 0, 0);
            const float bias = b_op[col];
#pragma unroll
            for (int r = 0; r < 4; ++r)
                zb_op[(size_t)(orow + r) * OUT + col] = f32_to_bf16_rtne(acc[r] + bias);
        }
        {
            const bf16x8 u0 = *reinterpret_cast<const bf16x8*>(Ub_op + (size_t)li * IN_OP + lg * 8);
            const bf16x8 u1 = *reinterpret_cast<const bf16x8*>(Ub_op + (size_t)li * IN_OP + lg * 8 + 32);
            f32x4 acc = {0.f, 0.f, 0.f, 0.f};
            acc = __builtin_amdgcn_mfma_f32_16x16x32_bf16(a0, u0, acc, 0, 0, 0);
            acc = __builtin_amdgcn_mfma_f32_16x16x32_bf16(a1, u1, acc, 0, 0, 0);
            const float cj = c_op[li];
#pragma unroll
            for (int r = 0; r < 4; ++r)
                p_op[(size_t)(orow + r) * 16 + li] = acc[r] + cj;
        }
    } else if (bid < GBA + GBB) {
        const int tile = (bid - GBA) * 4 + w;
        if (tile >= TILES_MAC) return;
        const int row0 = tile * 16;
        const float* hr = h_mac + (size_t)(row0 + li) * IN_MAC + lg * 8;
        const bf16x8 a0 = cvt8(*reinterpret_cast<const float4*>(hr),
                               *reinterpret_cast<const float4*>(hr + 4));
        const int orow = row0 + lg * 4;
#pragma unroll
        for (int ct = 0; ct < 8; ++ct) {
            const int col = ct * 16 + li;
            const float* wr = W_mac + (size_t)col * IN_MAC + lg * 8;
            const bf16x8 b0 = cvt8(*reinterpret_cast<const float4*>(wr),
                                   *reinterpret_cast<const float4*>(wr + 4));
            f32x4 acc = {0.f, 0.f, 0.f, 0.f};
            acc = __builtin_amdgcn_mfma_f32_16x16x32_bf16(a0, b0, acc, 0, 0, 0);
            const float bias = b_mac[col];
#pragma unroll
            for (int r = 0; r < 4; ++r)
                zb_mac[(size_t)(orow + r) * OUT + col] = f32_to_bf16_rtne(acc[r] + bias);
        }
        {
            const bf16x8 u0 = *reinterpret_cast<const bf16x8*>(Ub_mac + (size_t)li * IN_MAC + lg * 8);
            f32x4 acc = {0.f, 0.f, 0.f, 0.f};
            acc = __builtin_amdgcn_mfma_f32_16x16x32_bf16(a0, u0, acc, 0, 0, 0);
            if (li < 8) {
                const float cj = c_mac[li];
#pragma unroll
                for (int r = 0; r < 4; ++r)
                    p_mac[(size_t)(orow + r) * 8 + li] = acc[r] + cj;
            }
        }
    } else {
        const uint_t x = my_xcd();
        int* const cop = crep_op + x * N_OP;
        int* const com = crep_om + x * N_MAC;
        const int base = (bid - GBA - GBB) * 512 + t;
#pragma unroll
        for (int k = 0; k < 2; ++k) {
            const int ge = base + k * 256;
            int r;
            if (ge < E_SEQ) {
                r = l2_atomic_inc(&cop[seq_dst[ge]]);
                rank_all[ge] = (int)((x << 24) | (uint_t)r);
            } else if (ge < E_SM) {
                r = l2_atomic_inc(&cop[mo_dst[ge - E_SEQ]]);
                rank_all[ge] = (int)((x << 24) | (uint_t)r);
            } else if (ge < TOT_E) {
                r = l2_atomic_inc(&com[om_dst[ge - E_SM]]);
                rank_all[ge] = (int)((x << 24) | (uint_t)r);
            }
        }
    }
}

// ---------------------------------------------------------------------------
// K2: alloc. Per dst: total = sum of 8 replicas; wave-scan totals -> sta/end;
// per-replica bases brep[x][d] = sta[d] + prefix_x.
// ---------------------------------------------------------------------------
__global__ void k_alloc(const int* __restrict__ crep_op, int* __restrict__ sta_op, int* __restrict__ end_op, int* __restrict__ brep_op,
                        const int* __restrict__ crep_om, int* __restrict__ sta_om, int* __restrict__ end_om, int* __restrict__ brep_om,
                        int* __restrict__ ctr) {
    const int b = blockIdx.x, t = threadIdx.x;
    const int* crep; int* sta; int* end; int* brep; int n, g, lb;
    if (b < AB_OP) { crep = crep_op; sta = sta_op; end = end_op; brep = brep_op; n = N_OP;  g = 0; lb = b; }
    else           { crep = crep_om; sta = sta_om; end = end_om; brep = brep_om; n = N_MAC; g = 1; lb = b - AB_OP; }
    const int d = lb * 256 + t;
    const int lane = t & 63;
    int c[NXCD];
    int tot = 0;
#pragma unroll
    for (int x = 0; x < NXCD; ++x) {
        c[x] = (d < n) ? crep[x * n + d] : 0;
        tot += c[x];
    }
    int xs = tot;
#pragma unroll
    for (int m = 1; m < 64; m <<= 1) {
        int y = __shfl_up(xs, m);
        if (lane >= m) xs += y;
    }
    int base = 0;
    if (lane == 63) base = atomicAdd(&ctr[g], xs);
    base = __shfl(base, 63);
    if (d < n) {
        const int s = base + xs - tot;
        sta[d] = s;
        end[d] = s + tot;
        int acc = s;
#pragma unroll
        for (int x = 0; x < NXCD; ++x) {
            brep[x * n + d] = acc;
            acc += c[x];
        }
    }
}

// ---------------------------------------------------------------------------
// Fill body: record {arena_row|flag<<31, al01, al23, 0};
// pos = brep[xcd][d] + local_rank.
// ---------------------------------------------------------------------------
__device__ __forceinline__ void fill_one(uint_t rowtag, int d, float f,
                                         const float* __restrict__ ps, int pso,
                                         const float* __restrict__ pd, int pdo,
                                         const float* __restrict__ att,
                                         const int* __restrict__ brep, int n, int ri,
                                         uint4* __restrict__ rec) {
    const float4 as = *reinterpret_cast<const float4*>(ps + pso);
    const float4 ad = *reinterpret_cast<const float4*>(pd + pdo);
    const float4 aw = make_float4(att[64], att[ATT_DIM + 64], att[2 * ATT_DIM + 64], att[3 * ATT_DIM + 64]);
    const float sc[4] = {as.x + ad.x + f * aw.x, as.y + ad.y + f * aw.y,
                         as.z + ad.z + f * aw.z, as.w + ad.w + f * aw.w};
    uint_t b16[4];
#pragma unroll
    for (int hh = 0; hh < 4; ++hh) {
        float v = sc[hh];
        v = (v >= 0.f) ? v : 0.2f * v;
        v = fminf(fmaxf(v, -20.f), 20.f);
        b16[hh] = f32_to_bf16_rtne(expf(v));
    }
    const int xcd = ((uint_t)ri) >> 24;
    const int rank = ri & 0xFFFFFF;
    const int pos = brep[xcd * n + d] + rank;
    uint4 r;
    r.x = rowtag;
    r.y = b16[0] | (b16[1] << 16);
    r.z = b16[2] | (b16[3] << 16);
    r.w = 0;
    rec[pos] = r;
}

// K3: fill, all three graphs (seq+mo -> rec_op with flag, om -> rec_om).
__global__ void k_fill(
    const int* __restrict__ seq_src, const int* __restrict__ seq_dst, const float* __restrict__ feat_seq,
    const int* __restrict__ mo_src,  const int* __restrict__ mo_dst,  const float* __restrict__ feat_mo,
    const int* __restrict__ om_src,  const int* __restrict__ om_dst,  const float* __restrict__ feat_om,
    const float* __restrict__ p_op, const float* __restrict__ p_mac,
    const float* __restrict__ att_seq, const float* __restrict__ att_mo, const float* __restrict__ att_om,
    const int* __restrict__ brep_op, const int* __restrict__ brep_om,
    const int* __restrict__ rank_all,
    uint4* __restrict__ rec_op, uint4* __restrict__ rec_om) {
    const int ge = blockIdx.x * 256 + threadIdx.x;
    if (ge < E_SEQ) {
        const int s = seq_src[ge], d = seq_dst[ge];
        fill_one((uint_t)s, d, feat_seq[ge], p_op, s * 16 + 0, p_op, d * 16 + 4,
                 att_seq, brep_op, N_OP, rank_all[ge], rec_op);
    } else if (ge < E_SM) {
        const int e = ge - E_SEQ;
        const int s = mo_src[e], d = mo_dst[e];
        fill_one((uint_t)(N_OP + s) | 0x80000000u, d, feat_mo[e], p_mac, s * 8 + 4,
                 p_op, d * 16 + 12, att_mo, brep_op, N_OP, rank_all[ge], rec_op);
    } else if (ge < TOT_E) {
        const int e = ge - E_SM;
        const int s = om_src[e], d = om_dst[e];
        fill_one((uint_t)s, d, feat_om[e], p_op, s * 16 + 8, p_mac, d * 8 + 0,
                 att_om, brep_om, N_MAC, rank_all[ge], rec_om);
    }
}

// ---------------------------------------------------------------------------
// Gather helpers.
// ---------------------------------------------------------------------------
__device__ __forceinline__ float2 ln_elu2(float x0, float x1, int lane,
                                          const float* __restrict__ g,
                                          const float* __restrict__ bb, int col2) {
    float s = x0 + x1;
#pragma unroll
    for (int m = 32; m >= 1; m >>= 1) s += __shfl_xor(s, m);
    const float mu = s * (1.0f / OUT);
    const float dx0 = x0 - mu, dx1 = x1 - mu;
    float q = dx0 * dx0 + dx1 * dx1;
#pragma unroll
    for (int m = 32; m >= 1; m >>= 1) q += __shfl_xor(q, m);
    const float r = rsqrtf(q * (1.0f / OUT) + LN_EPS);
    const float2 g2 = *reinterpret_cast<const float2*>(g + col2);
    const float2 b2 = *reinterpret_cast<const float2*>(bb + col2);
    float y0 = dx0 * r * g2.x + b2.x;
    float y1 = dx1 * r * g2.y + b2.y;
    y0 = (y0 > 0.f) ? y0 : expm1f(y0);
    y1 = (y1 > 0.f) ? y1 : expm1f(y1);
    return make_float2(y0, y1);
}

__device__ __forceinline__ float2 unpack_bf2(uint_t zz) {
    return make_float2(__uint_as_float(zz << 16), __uint_as_float(zz & 0xffff0000u));
}

// Scalarized record-segment accumulate (R17): scalar loop index ->
// s_load_dwordx4 record fetch (SMEM queue), SALU decode, ~11 VALU/record.
__device__ __forceinline__ void seg_scalar(const uint4* __restrict__ rec,
                                           const ushort_t* __restrict__ arena,
                                           int s0, int e0, int wSel, int hiSel, int col2,
                                           float& ns0, float& ns1, float& nm0, float& nm1,
                                           float& ds, float& dm) {
#pragma unroll 8
    for (int i = s0; i < e0; ++i) {
        const uint4 r = rec[i];
        const int row = (int)(r.x & 0x7fffffffu);
        const uint_t isMo = r.x >> 31;
        const uint_t pick = wSel ? r.z : r.y;
        const float a = __uint_as_float(hiSel ? (pick & 0xffff0000u) : (pick << 16));
        const float a_s = isMo ? 0.f : a;
        const float a_m = isMo ? a : 0.f;
        const uint_t zz = *reinterpret_cast<const uint_t*>(arena + (size_t)row * OUT + col2);
        const float z0 = __uint_as_float(zz << 16);
        const float z1 = __uint_as_float(zz & 0xffff0000u);
        ns0 = fmaf(a_s, z0, ns0);
        ns1 = fmaf(a_s, z1, ns1);
        nm0 = fmaf(a_m, z0, nm0);
        nm1 = fmaf(a_m, z1, nm1);
        ds += a_s;
        dm += a_m;
    }
}

// ---------------------------------------------------------------------------
// K4: [gather_op (1 row/wave, scalar record loop) | gather_mac (1 block/row,
// each wave takes a contiguous quarter of the segment, scalar loop)].
// ---------------------------------------------------------------------------
__global__ void k_gather(
    const uint4* __restrict__ rec_op, const int* __restrict__ sta_op, const int* __restrict__ end_op,
    const uint4* __restrict__ rec_om, const int* __restrict__ sta_om, const int* __restrict__ end_om,
    const ushort_t* __restrict__ zb_op, const ushort_t* __restrict__ zb_mac,
    const float* __restrict__ g_op, const float* __restrict__ b_op,
    const float* __restrict__ g_mac, const float* __restrict__ b_mac,
    float* __restrict__ out_op, float* __restrict__ out_mac) {
    const int bid = blockIdx.x;
    const int t = threadIdx.x;
    const int w = __builtin_amdgcn_readfirstlane(t >> 6);
    const int lane = t & 63;
    const int hd = lane >> 4;
    const int col2 = lane * 2;
    const int wSel = hd >> 1, hiSel = hd & 1;
    __shared__ float nsh[4][OUT];
    __shared__ float dsh[4][2 * HEADS];

    if (bid < GOP_B) {
        const int d = __builtin_amdgcn_readfirstlane(bid * 4 + w);
        if (d >= N_OP) return;
        const int s0 = sta_op[d], e0 = end_op[d];
        float ns0 = 0.f, ns1 = 0.f, nm0 = 0.f, nm1 = 0.f, ds = 0.f, dm = 0.f;
        seg_scalar(rec_op, zb_op, s0, e0, wSel, hiSel, col2, ns0, ns1, nm0, nm1, ds, dm);
        const float invS = 1.0f / (ds + EPS);
        const float invM = 1.0f / (dm + EPS);
        const float acc0 = ns0 * invS + nm0 * invM;
        const float acc1 = ns1 * invS + nm1 * invM;
        const float2 zr = unpack_bf2(*reinterpret_cast<const uint_t*>(zb_op + (size_t)d * OUT + col2));
        const float2 o2 = ln_elu2(acc0 + zr.x, acc1 + zr.y, lane, g_op, b_op, col2);
        *reinterpret_cast<float2*>(out_op + (size_t)d * OUT + col2) = o2;
    } else {
        const int d = __builtin_amdgcn_readfirstlane(bid - GOP_B);
        const int s0 = sta_om[d], e0 = end_om[d];
        const int len = e0 - s0;
        const int quarter = (len + 3) >> 2;
        const int i0 = s0 + w * quarter;
        int i1 = i0 + quarter;
        if (i1 > e0) i1 = e0;
        float ns0 = 0.f, ns1 = 0.f, nm0 = 0.f, nm1 = 0.f, ds = 0.f, dm = 0.f;
        if (i0 < e0)
            seg_scalar(rec_om, zb_op, i0, i1, wSel, hiSel, col2, ns0, ns1, nm0, nm1, ds, dm);
        nsh[w][col2] = ns0;
        nsh[w][col2 + 1] = ns1;
        if ((lane & 15) == 0) dsh[w][hd] = ds;
        __syncthreads();
        if (w == 0) {
            const float n0 = nsh[0][col2] + nsh[1][col2] + nsh[2][col2] + nsh[3][col2];
            const float n1 = nsh[0][col2 + 1] + nsh[1][col2 + 1] + nsh[2][col2 + 1] + nsh[3][col2 + 1];
            const float dt = dsh[0][hd] + dsh[1][hd] + dsh[2][hd] + dsh[3][hd];
            const float inv = 1.0f / (dt + EPS);
            const float2 zr = unpack_bf2(*reinterpret_cast<const uint_t*>(zb_mac + (size_t)d * OUT + col2));
            const float2 o2 = ln_elu2(n0 * inv + zr.x, n1 * inv + zr.y, lane, g_mac, b_mac, col2);
            *reinterpret_cast<float2*>(out_mac + (size_t)d * OUT + col2) = o2;
        }
    }
}

extern "C" void kernel_launch(void* const* d_in, const int* in_sizes, int n_in,
                              void* d_out, int out_size, void* d_ws, size_t ws_size,
                              hipStream_t stream) {
    const float* h_op      = (const float*)d_in[0];
    const float* h_mac     = (const float*)d_in[1];
    const int*   seq_src   = (const int*)d_in[2];
    const int*   seq_dst   = (const int*)d_in[3];
    const int*   om_src    = (const int*)d_in[4];
    const int*   om_dst    = (const int*)d_in[5];
    const int*   mo_src    = (const int*)d_in[6];
    const int*   mo_dst    = (const int*)d_in[7];
    const float* feat_seq  = (const float*)d_in[8];
    const float* feat_om   = (const float*)d_in[9];
    const float* feat_mo   = (const float*)d_in[10];
    const float* W_op_w    = (const float*)d_in[11];
    const float* W_op_b    = (const float*)d_in[12];
    const float* W_mac_w   = (const float*)d_in[13];
    const float* W_mac_b   = (const float*)d_in[14];
    const float* att_seq   = (const float*)d_in[15];
    const float* att_om    = (const float*)d_in[16];
    const float* att_mo    = (const float*)d_in[17];
    const float* ln_op_g   = (const float*)d_in[18];
    const float* ln_op_b   = (const float*)d_in[19];
    const float* ln_mac_g  = (const float*)d_in[20];
    const float* ln_mac_b  = (const float*)d_in[21];

    float* p = (float*)d_ws;
    float* p_op   = p; p += (size_t)N_OP * 16;
    float* p_mac  = p; p += (size_t)N_MAC * 8;
    float* c_op   = p; p += 16;
    float* c_mac  = p; p += 16;
    uint4* rec_op = (uint4*)p; p += (size_t)E_SM * 4;
    uint4* rec_om = (uint4*)p; p += (size_t)E_OM * 4;
    ushort_t* zb_op  = (ushort_t*)p; p += (size_t)N_OP * OUT / 2;
    ushort_t* zb_mac = (ushort_t*)p; p += (size_t)N_MAC * OUT / 2;
    ushort_t* Ub_op  = (ushort_t*)p; p += 16 * IN_OP / 2;
    ushort_t* Ub_mac = (ushort_t*)p; p += 16 * IN_MAC / 2;
    int* q = (int*)p;
    int* crep_op = q; q += NXCD * N_OP;
    int* crep_om = q; q += NXCD * N_MAC;
    int* ctr     = q; q += 4;
    int* sta_op = q; q += N_OP;
    int* sta_om = q; q += N_MAC;
    int* end_op = q; q += N_OP;
    int* end_om = q; q += N_MAC;
    int* brep_op = q; q += NXCD * N_OP;
    int* brep_om = q; q += NXCD * N_MAC;
    int* rank_all = q; q += TOT_E;

    float* out_op  = (float*)d_out;
    float* out_mac = (float*)d_out + (size_t)N_OP * OUT;

    k_fold_zero<<<64, 256, 0, stream>>>(W_op_w, W_op_b, W_mac_w, W_mac_b,
                                        att_seq, att_om, att_mo,
                                        c_op, c_mac, Ub_op, Ub_mac, crep_op);

    k_gemm_histo<<<GBA + GBB + HBK, 256, 0, stream>>>(
        h_op, W_op_w, W_op_b, h_mac, W_mac_w, W_mac_b,
        Ub_op, c_op, Ub_mac, c_mac,
        zb_op, zb_mac, p_op, p_mac,
        seq_dst, mo_dst, om_dst, crep_op, crep_om, rank_all);

    k_alloc<<<AB_TOT, 256, 0, stream>>>(
        crep_op, sta_op, end_op, brep_op,
        crep_om, sta_om, end_om, brep_om, ctr);

    k_fill<<<FALL_B, 256, 0, stream>>>(
        seq_src, seq_dst, feat_seq, mo_src, mo_dst, feat_mo, om_src, om_dst, feat_om,
        p_op, p_mac, att_seq, att_mo, att_om,
        brep_op, brep_om, rank_all,
        rec_op, rec_om);

    k_gather<<<GOP_B + N_MAC, 256, 0, stream>>>(
        rec_op, sta_op, end_op,
        rec_om, sta_om, end_om,
        zb_op, zb_mac,
        ln_op_g, ln_op_b, ln_mac_g, ln_mac_b,
        out_op, out_mac);
}